// Round 1
// baseline (1011.181 us; speedup 1.0000x reference)
//
#include <hip/hip_runtime.h>
#include <hip/hip_cooperative_groups.h>
#include <math.h>

namespace cg = cooperative_groups;

// Problem constants (from reference)
#define NN 100000          // nodes
#define LF 48              // features per node
#define NE 1600000         // edges
#define EDIMS 17           // edge_attr dim
#define MASKW 3125         // NN/32 bitmask words
#define CAP_E 16384        // per-level edge-list capacity (expected ~5k max level)
#define MAXLOC 12288       // active-node capacity (expected ~4.9k)
#define BLK 256
#define GRID_MAX 1024      // 4 blocks/CU x 256 CUs -- guaranteed co-resident w/ launch_bounds(256,4)

static_assert(NN == MASKW * 32, "mask width");
static_assert((CAP_E & (CAP_E - 1)) == 0, "CAP_E pow2");

struct Params {
    const float* nodes; const float* valid; const float* eattr;
    const int* src; const int* dst;
    const float *W1, *b1, *W2, *b2, *Wg, *bg, *Ww, *bw, *Wf, *bf;
    int* counters;                 // [0]=|E3| [1]=|E2| [2]=|E1| [3]=nloc
    unsigned *M3, *M2, *M1, *M0;   // S3={0}; S2=S3∪src(E3); S1=S2∪src(E2); S0 active set
    int *n2l, *l2n;
    int4* lists;                   // slot0=E3, slot1=E2, slot2=E1
    float *X0, *XA, *XB, *VA, *VB, *MVA, *MVB;
    float *agg;                    // 3 contiguous buffers, pre-zeroed in P0
    float* out;
};

__device__ __forceinline__ float gelu_f(float x) {
    // jax.nn.gelu(approximate=False) = x * 0.5 * (1 + erf(x/sqrt(2)))
    return 0.5f * x * (1.0f + erff(x * 0.7071067811865475f));
}
__device__ __forceinline__ float sigm_f(float x) {
    return 1.0f / (1.0f + expf(-x));
}

// ---- phase bodies (each internally sync-free; separated by grid syncs) ----

// Mout (pre-zeroed) := Min | src-bits of selected edges; append selected edges to list.
// Copy is done with atomicOr so it can run concurrently with the edge scan.
__device__ void expand_phase(const Params& p, const unsigned* __restrict__ Min,
                             unsigned* __restrict__ Mout, int4* __restrict__ list,
                             int* __restrict__ counter, int tid, int nthr)
{
    for (int w = tid; w < MASKW; w += nthr) atomicOr(&Mout[w], Min[w]);
    for (int e = tid; e < NE; e += nthr) {
        int d = p.dst[e];
        if (Min[d >> 5] & (1u << (d & 31))) {
            int s = p.src[e];
            int idx = atomicAdd(counter, 1);
            if (idx < CAP_E) list[idx] = make_int4(s, d, e, 0);
            atomicOr(&Mout[s >> 5], 1u << (s & 31));
        }
    }
}

// One wave (64 lanes) per listed edge: loop-invariant scalar
//   w0 = gelu(relu(gelu(ea@W1+b1)@W2+b2)@Wg+bg)@Ww + bw
// shared-memory staging replaced by wave __shfl broadcasts (no __syncthreads, no LDS).
__device__ void w0_edge(const Params& p, int4* __restrict__ entp, int lane)
{
    int4 ent = *entp;
    float ea = 0.f;
    if (lane < EDIMS) ea = p.eattr[(long)ent.z * EDIMS + lane];
    float h1 = 0.f;
    if (lane < 48) {
        float acc = p.b1[lane];
        #pragma unroll
        for (int k = 0; k < EDIMS; ++k) acc += __shfl(ea, k, 64) * p.W1[k * 48 + lane];
        h1 = gelu_f(acc);
    }
    float h2 = 0.f;
    if (lane < 48) {
        float acc = p.b2[lane];
        #pragma unroll 8
        for (int k = 0; k < 48; ++k) acc += __shfl(h1, k, 64) * p.W2[k * 48 + lane];
        h2 = fmaxf(acc, 0.f);
    }
    float part = 0.f;
    if (lane < 48) {
        float acc = p.bg[lane];
        #pragma unroll 8
        for (int k = 0; k < 48; ++k) acc += __shfl(h2, k, 64) * p.Wg[k * 48 + lane];
        part = gelu_f(acc) * p.Ww[lane];
    }
    #pragma unroll
    for (int off = 32; off > 0; off >>= 1) part += __shfl_down(part, off, 64);
    if (lane == 0) {
        float w0 = part + p.bw[0];
        int sl = p.n2l[ent.x]; if ((unsigned)sl >= MAXLOC) sl = 0;
        int dl = p.n2l[ent.y]; if ((unsigned)dl >= MAXLOC) dl = 0;
        *entp = make_int4(sl, dl, ent.z, __float_as_int(w0));
    }
}

// agg[dst] += sigmoid(meanv[src]*w0) * x_prev[src]  (one wave per edge, 48 active lanes)
__device__ void agg_phase(const Params& p, const int4* __restrict__ list,
                          const int* __restrict__ cnt, const float* __restrict__ Xprev,
                          const float* __restrict__ MVprev, float* __restrict__ agg,
                          int tid, int nthr)
{
    int c = *cnt; if (c > CAP_E) c = CAP_E;
    int lane = tid & 63;
    for (int i = tid >> 6; i < c; i += (nthr >> 6)) {
        int4 ent = list[i];
        if ((unsigned)ent.x >= MAXLOC || (unsigned)ent.y >= MAXLOC) continue;
        float s = sigm_f(MVprev[ent.x] * __int_as_float(ent.w));
        if (lane < 48) atomicAdd(&agg[ent.y * LF + lane], s * Xprev[ent.x * LF + lane]);
    }
}

// m = sigmoid(nh*Wf0 + x*Wf1 + nv*Wf2 + bf); x' = (1-m)x + nv*m*nh;
// v' = (orig != x') | (v>0); v'[:,0]=0; meanv' = mean(v')    — nodes in mask Mt only
__device__ void update_phase(const Params& p, const unsigned* __restrict__ Mt,
                             const float* __restrict__ agg, const float* __restrict__ Xprev,
                             const float* __restrict__ Vprev, float* __restrict__ Xcur,
                             float* __restrict__ Vcur, float* __restrict__ MVcur,
                             int tid, int nthr)
{
    int nl = p.counters[3]; if (nl > MAXLOC) nl = MAXLOC;
    float wf0 = p.Wf[0], wf1 = p.Wf[1], wf2 = p.Wf[2], bfs = p.bf[0];
    for (int loc = tid; loc < nl; loc += nthr) {
        int node = p.l2n[loc];
        if (!(Mt[node >> 5] & (1u << (node & 31)))) continue;
        float vsum = 0.f;
        #pragma unroll 4
        for (int l = 0; l < LF; ++l) {
            float nh = agg[loc * LF + l];
            float xo = Xprev[loc * LF + l];
            float vp = Vprev[loc * LF + l];
            float nv = 1.0f - vp;
            float m = sigm_f(nh * wf0 + xo * wf1 + nv * wf2 + bfs);
            float xn = (1.0f - m) * xo + nv * m * nh;
            float vn = ((p.X0[loc * LF + l] != xn) || (vp > 0.f)) ? 1.0f : 0.0f;
            if (l == 0) vn = 0.0f;
            Xcur[loc * LF + l] = xn;
            Vcur[loc * LF + l] = vn;
            vsum += vn;
        }
        MVcur[loc] = vsum * (1.0f / 48.0f);
    }
}

__device__ void run_phase(const Params& p, int ph, int tid, int nthr)
{
    float* agg0 = p.agg;
    float* agg1 = p.agg + MAXLOC * LF;
    float* agg2 = p.agg + 2 * MAXLOC * LF;
    switch (ph) {
    case 0: { // zero counters/masks/aggs + seed node 0 into M3
        if (tid < 4) p.counters[tid] = 0;
        for (int i = tid; i < MASKW; i += nthr) {
            p.M3[i] = (i == 0) ? 1u : 0u;
            p.M2[i] = 0u; p.M1[i] = 0u; p.M0[i] = 0u;
        }
        for (int i = tid; i < 3 * MAXLOC * LF; i += nthr) p.agg[i] = 0.f;
    } break;
    case 1: expand_phase(p, p.M3, p.M2, p.lists + 0 * CAP_E, p.counters + 0, tid, nthr); break;
    case 2: expand_phase(p, p.M2, p.M1, p.lists + 1 * CAP_E, p.counters + 1, tid, nthr); break;
    case 3: expand_phase(p, p.M1, p.M0, p.lists + 2 * CAP_E, p.counters + 2, tid, nthr); break;
    case 4: { // compact M0 -> n2l/l2n
        for (int w = tid; w < MASKW; w += nthr) {
            unsigned bits = p.M0[w];
            while (bits) {
                int b = __ffs(bits) - 1;
                bits &= bits - 1;
                int node = w * 32 + b;
                int loc = atomicAdd(p.counters + 3, 1);
                if (loc < MAXLOC) { p.n2l[node] = loc; p.l2n[loc] = node; }
            }
        }
    } break;
    case 5: { // init X0/VA/MVA for active nodes + per-edge loop-invariant w0 for all 3 lists
        int nl = p.counters[3]; if (nl > MAXLOC) nl = MAXLOC;
        for (int loc = tid; loc < nl; loc += nthr) {
            int node = p.l2n[loc];
            const float4* nv = (const float4*)(p.valid + (size_t)node * LF);
            const float4* nx = (const float4*)(p.nodes + (size_t)node * LF);
            float4* X0v = (float4*)(p.X0 + (size_t)loc * LF);
            float4* V0v = (float4*)(p.VA + (size_t)loc * LF);
            float sum = 0.f;
            #pragma unroll
            for (int k = 0; k < 12; ++k) {
                float4 v = nv[k], x = nx[k];
                x.x *= v.x; x.y *= v.y; x.z *= v.z; x.w *= v.w;
                X0v[k] = x; V0v[k] = v;
                sum += v.x + v.y + v.z + v.w;
            }
            p.MVA[loc] = sum * (1.0f / 48.0f);
        }
        int c0 = p.counters[0]; c0 = (c0 > CAP_E) ? CAP_E : c0;
        int c1 = p.counters[1]; c1 = (c1 > CAP_E) ? CAP_E : c1;
        int c2 = p.counters[2]; c2 = (c2 > CAP_E) ? CAP_E : c2;
        int total = c0 + c1 + c2;
        int lane = tid & 63;
        for (int g = tid >> 6; g < total; g += (nthr >> 6)) {
            int4* entp;
            if (g < c0)           entp = p.lists + g;
            else if (g < c0 + c1) entp = p.lists + CAP_E + (g - c0);
            else                  entp = p.lists + 2 * CAP_E + (g - c0 - c1);
            w0_edge(p, entp, lane);
        }
    } break;
    // iter 1: prev X0/VA/MVA -> XA/VB/MVB, edges E1 (slot2), nodes M1
    case 6:  agg_phase(p, p.lists + 2 * CAP_E, p.counters + 2, p.X0, p.MVA, agg0, tid, nthr); break;
    case 7:  update_phase(p, p.M1, agg0, p.X0, p.VA, p.XA, p.VB, p.MVB, tid, nthr); break;
    // iter 2: XA/VB/MVB -> XB/VA/MVA, edges E2 (slot1), nodes M2
    case 8:  agg_phase(p, p.lists + 1 * CAP_E, p.counters + 1, p.XA, p.MVB, agg1, tid, nthr); break;
    case 9:  update_phase(p, p.M2, agg1, p.XA, p.VB, p.XB, p.VA, p.MVA, tid, nthr); break;
    // iter 3: XB/VA/MVA -> XA/VB/MVB, edges E3 (slot0), nodes M3 (= node 0)
    case 10: agg_phase(p, p.lists + 0 * CAP_E, p.counters + 0, p.XB, p.MVA, agg2, tid, nthr); break;
    case 11: update_phase(p, p.M3, agg2, p.XB, p.VA, p.XA, p.VB, p.MVB, tid, nthr); break;
    case 12: { // output
        if (tid < 48) p.out[tid] = p.XA[(size_t)p.n2l[0] * 48 + tid];
    } break;
    }
}

__global__ void __launch_bounds__(BLK, 4) fused_kernel(Params p)
{
    cg::grid_group grid = cg::this_grid();
    int tid = blockIdx.x * BLK + threadIdx.x;
    int nthr = (int)gridDim.x * BLK;
    for (int ph = 0; ph < 13; ++ph) {
        run_phase(p, ph, tid, nthr);
        if (ph < 12) grid.sync();
    }
}

// Fallback: each phase is internally sync-free, so it can run as an ordinary kernel.
__global__ void __launch_bounds__(BLK) phase_kernel(Params p, int ph)
{
    run_phase(p, ph, blockIdx.x * BLK + threadIdx.x, (int)gridDim.x * BLK);
}

extern "C" void kernel_launch(void* const* d_in, const int* in_sizes, int n_in,
                              void* d_out, int out_size, void* d_ws, size_t ws_size,
                              hipStream_t stream)
{
    (void)in_sizes; (void)n_in; (void)out_size;
    const float* nodes = (const float*)d_in[0];
    const int*   eidx  = (const int*)d_in[1];     // (2,E) int32
    const float* eattr = (const float*)d_in[2];
    const float* valid = (const float*)d_in[3];
    // d_in[4]=r, d_in[5]=fx unused by reference
    Params hp;
    hp.nodes = nodes; hp.valid = valid; hp.eattr = eattr;
    hp.src = eidx; hp.dst = eidx + NE;
    hp.W1 = (const float*)d_in[6];  hp.b1 = (const float*)d_in[7];
    hp.W2 = (const float*)d_in[8];  hp.b2 = (const float*)d_in[9];
    hp.Wg = (const float*)d_in[10]; hp.bg = (const float*)d_in[11];
    hp.Ww = (const float*)d_in[12]; hp.bw = (const float*)d_in[13];
    hp.Wf = (const float*)d_in[14]; hp.bf = (const float*)d_in[15];

    char* ws = (char*)d_ws;
    size_t off = 0;
    auto alloc = [&](size_t bytes) -> char* {
        char* ptr = ws + off;
        off += (bytes + 255) & ~(size_t)255;
        return ptr;
    };
    hp.counters = (int*)alloc(64);
    hp.M3 = (unsigned*)alloc(MASKW * 4);
    hp.M2 = (unsigned*)alloc(MASKW * 4);
    hp.M1 = (unsigned*)alloc(MASKW * 4);
    hp.M0 = (unsigned*)alloc(MASKW * 4);
    hp.n2l = (int*)alloc((size_t)NN * 4);
    hp.l2n = (int*)alloc((size_t)MAXLOC * 4);
    hp.lists = (int4*)alloc((size_t)3 * CAP_E * 16);
    hp.X0 = (float*)alloc((size_t)MAXLOC * LF * 4);
    hp.XA = (float*)alloc((size_t)MAXLOC * LF * 4);
    hp.XB = (float*)alloc((size_t)MAXLOC * LF * 4);
    hp.VA = (float*)alloc((size_t)MAXLOC * LF * 4);
    hp.VB = (float*)alloc((size_t)MAXLOC * LF * 4);
    hp.MVA = (float*)alloc((size_t)MAXLOC * 4);
    hp.MVB = (float*)alloc((size_t)MAXLOC * 4);
    hp.agg = (float*)alloc((size_t)3 * MAXLOC * LF * 4);
    hp.out = (float*)d_out;
    if (off > ws_size) return;   // ~23 MB needed; fail loudly rather than corrupt

    // Grid: guaranteed-co-resident size (launch_bounds(256,4) => >=4 blocks/CU, LDS=0).
    int grid = GRID_MAX;
    int maxBlk = 0;
    if (hipOccupancyMaxActiveBlocksPerMultiprocessor(
            &maxBlk, reinterpret_cast<const void*>(&fused_kernel), BLK, 0) == hipSuccess
        && maxBlk > 0) {
        int cap = maxBlk * 256;              // MI355X: 256 CUs
        if (grid > cap) grid = cap;
        if (grid < 1) grid = 1;
    }

    void* args[] = { &hp };
    hipError_t err = hipLaunchCooperativeKernel(
        reinterpret_cast<const void*>(&fused_kernel),
        dim3(grid), dim3(BLK), args, 0, stream);
    if (err != hipSuccess) {
        // Fallback: sequential phase launches (same math, ordinary kernels).
        for (int ph = 0; ph < 13; ++ph)
            phase_kernel<<<GRID_MAX, BLK, 0, stream>>>(hp, ph);
    }
}

// Round 2
// 395.871 us; speedup vs baseline: 2.5543x; 2.5543x over previous
//
#include <hip/hip_runtime.h>
#include <math.h>

// Problem constants (from reference)
#define NN 100000          // nodes
#define LF 48              // features per node
#define NE 1600000         // edges
#define EDIMS 17           // edge_attr dim
#define MASKW 3125         // NN/32 bitmask words
#define CAP_E 16384        // per-level edge-list capacity (expected ~5k max level)
#define MAXLOC 12288       // active-node capacity (expected ~4.9k)
#define EB 1563            // expand grid: ceil(NE/4/256), 4 edges/thread via int4

static_assert(NN == MASKW * 32, "mask width");

__device__ __forceinline__ float gelu_f(float x) {
    // jax.nn.gelu(approximate=False) = x * 0.5 * (1 + erf(x/sqrt(2)))
    return 0.5f * x * (1.0f + erff(x * 0.7071067811865475f));
}
__device__ __forceinline__ float sigm_f(float x) {
    return 1.0f / (1.0f + expf(-x));
}

// Level-3 expand: S3 = {0} is implicit (test dst==0, no mask read, no seed kernel).
// Also folds zero-init of M1, M0 and the three agg buffers (consumed by later kernels).
__global__ void expand1_kernel(const int* __restrict__ src, const int* __restrict__ dst,
                               unsigned* __restrict__ M2, unsigned* __restrict__ M1,
                               unsigned* __restrict__ M0, float4* __restrict__ aggz,
                               int4* __restrict__ list0, int* __restrict__ counter)
{
    int tid = blockIdx.x * 256 + threadIdx.x;
    int nthr = (int)gridDim.x * 256;
    for (int i = tid; i < MASKW; i += nthr) { M1[i] = 0u; M0[i] = 0u; }
    for (int i = tid; i < (3 * MAXLOC * LF) / 4; i += nthr)
        aggz[i] = make_float4(0.f, 0.f, 0.f, 0.f);
    if (tid == 0) atomicOr(&M2[0], 1u);   // S2 ⊇ S3 = {0}
    int e0 = tid * 4;
    if (e0 + 3 < NE) {
        int4 d4 = *(const int4*)(dst + e0);
        int dv[4] = { d4.x, d4.y, d4.z, d4.w };
        #pragma unroll
        for (int k = 0; k < 4; ++k) {
            if (dv[k] == 0) {
                int e = e0 + k;
                int s = src[e];
                int idx = atomicAdd(counter, 1);
                if (idx < CAP_E) list0[idx] = make_int4(s, 0, e, 0);
                atomicOr(&M2[s >> 5], 1u << (s & 31));
            }
        }
    } else {
        for (int e = e0; e < NE; ++e) {
            if (dst[e] == 0) {
                int s = src[e];
                int idx = atomicAdd(counter, 1);
                if (idx < CAP_E) list0[idx] = make_int4(s, 0, e, 0);
                atomicOr(&M2[s >> 5], 1u << (s & 31));
            }
        }
    }
}

// Generic expand: Mout (pre-zeroed) := Min | src-bits of selected edges; append edges.
__global__ void expand_kernel(const int* __restrict__ src, const int* __restrict__ dst,
                              const unsigned* __restrict__ Min, unsigned* __restrict__ Mout,
                              int4* __restrict__ list, int* __restrict__ counter)
{
    int tid = blockIdx.x * 256 + threadIdx.x;
    int nthr = (int)gridDim.x * 256;
    for (int i = tid; i < MASKW; i += nthr) {
        unsigned m = Min[i];
        if (m) atomicOr(&Mout[i], m);
    }
    int e0 = tid * 4;
    if (e0 + 3 < NE) {
        int4 d4 = *(const int4*)(dst + e0);
        int dv[4] = { d4.x, d4.y, d4.z, d4.w };
        #pragma unroll
        for (int k = 0; k < 4; ++k) {
            int d = dv[k];
            if (Min[d >> 5] & (1u << (d & 31))) {
                int e = e0 + k;
                int s = src[e];
                int idx = atomicAdd(counter, 1);
                if (idx < CAP_E) list[idx] = make_int4(s, d, e, 0);
                atomicOr(&Mout[s >> 5], 1u << (s & 31));
            }
        }
    } else {
        for (int e = e0; e < NE; ++e) {
            int d = dst[e];
            if (Min[d >> 5] & (1u << (d & 31))) {
                int s = src[e];
                int idx = atomicAdd(counter, 1);
                if (idx < CAP_E) list[idx] = make_int4(s, d, e, 0);
                atomicOr(&Mout[s >> 5], 1u << (s & 31));
            }
        }
    }
}

__global__ void compact_kernel(const unsigned* __restrict__ M0, int* __restrict__ n2l,
                               int* __restrict__ l2n, int* __restrict__ nloc)
{
    int w = blockIdx.x * 256 + threadIdx.x;
    if (w >= MASKW) return;
    unsigned bits = M0[w];
    while (bits) {
        int b = __ffs(bits) - 1;
        bits &= bits - 1;
        int node = w * 32 + b;
        int loc = atomicAdd(nloc, 1);
        if (loc < MAXLOC) { n2l[node] = loc; l2n[loc] = node; }
    }
}

// One wave per listed edge: loop-invariant scalar
//   w0 = gelu(relu(gelu(ea@W1+b1)@W2+b2)@Wg+bg)@Ww + bw
// via wave __shfl broadcasts (no __syncthreads, no LDS); remap ids -> local.
__device__ void w0_edge(int4* __restrict__ entp, const int* __restrict__ n2l,
                        const float* __restrict__ ea_g,
                        const float* __restrict__ W1, const float* __restrict__ b1,
                        const float* __restrict__ W2, const float* __restrict__ b2,
                        const float* __restrict__ Wg, const float* __restrict__ bg,
                        const float* __restrict__ Ww, const float* __restrict__ bw,
                        int lane)
{
    int4 ent = *entp;
    float ea = 0.f;
    if (lane < EDIMS) ea = ea_g[(long)ent.z * EDIMS + lane];
    float h1 = 0.f;
    if (lane < 48) {
        float acc = b1[lane];
        #pragma unroll
        for (int k = 0; k < EDIMS; ++k) acc += __shfl(ea, k, 64) * W1[k * 48 + lane];
        h1 = gelu_f(acc);
    }
    float h2 = 0.f;
    if (lane < 48) {
        float acc = b2[lane];
        #pragma unroll 8
        for (int k = 0; k < 48; ++k) acc += __shfl(h1, k, 64) * W2[k * 48 + lane];
        h2 = fmaxf(acc, 0.f);
    }
    float part = 0.f;
    if (lane < 48) {
        float acc = bg[lane];
        #pragma unroll 8
        for (int k = 0; k < 48; ++k) acc += __shfl(h2, k, 64) * Wg[k * 48 + lane];
        part = gelu_f(acc) * Ww[lane];
    }
    #pragma unroll
    for (int off = 32; off > 0; off >>= 1) part += __shfl_down(part, off, 64);
    if (lane == 0) {
        float w0 = part + bw[0];
        int sl = n2l[ent.x]; if ((unsigned)sl >= MAXLOC) sl = 0;
        int dl = n2l[ent.y]; if ((unsigned)dl >= MAXLOC) dl = 0;
        *entp = make_int4(sl, dl, ent.z, __float_as_int(w0));
    }
}

// Fused: per-active-node init (x0 = nodes*valid, v0, meanv0) + per-edge w0 for all 3 lists.
__global__ void initw0_kernel(const int* __restrict__ counters, const int* __restrict__ l2n,
                              const int* __restrict__ n2l,
                              const float* __restrict__ nodes, const float* __restrict__ valid,
                              float* __restrict__ X0, float* __restrict__ V0,
                              float* __restrict__ MV0,
                              int4* __restrict__ lists, const float* __restrict__ ea_g,
                              const float* __restrict__ W1, const float* __restrict__ b1,
                              const float* __restrict__ W2, const float* __restrict__ b2,
                              const float* __restrict__ Wg, const float* __restrict__ bg,
                              const float* __restrict__ Ww, const float* __restrict__ bw)
{
    int tid = blockIdx.x * 256 + threadIdx.x;
    int nthr = (int)gridDim.x * 256;
    int nl = counters[3]; if (nl > MAXLOC) nl = MAXLOC;
    for (int loc = tid; loc < nl; loc += nthr) {
        int node = l2n[loc];
        const float4* nv = (const float4*)(valid + (size_t)node * LF);
        const float4* nx = (const float4*)(nodes + (size_t)node * LF);
        float4* X0v = (float4*)(X0 + (size_t)loc * LF);
        float4* V0v = (float4*)(V0 + (size_t)loc * LF);
        float sum = 0.f;
        #pragma unroll
        for (int k = 0; k < 12; ++k) {
            float4 v = nv[k], x = nx[k];
            x.x *= v.x; x.y *= v.y; x.z *= v.z; x.w *= v.w;
            X0v[k] = x; V0v[k] = v;
            sum += v.x + v.y + v.z + v.w;
        }
        MV0[loc] = sum * (1.0f / 48.0f);
    }
    int c0 = counters[0]; c0 = (c0 > CAP_E) ? CAP_E : c0;
    int c1 = counters[1]; c1 = (c1 > CAP_E) ? CAP_E : c1;
    int c2 = counters[2]; c2 = (c2 > CAP_E) ? CAP_E : c2;
    int total = c0 + c1 + c2;
    int lane = tid & 63;
    for (int g = tid >> 6; g < total; g += (nthr >> 6)) {
        int4* entp;
        if (g < c0)           entp = lists + g;
        else if (g < c0 + c1) entp = lists + CAP_E + (g - c0);
        else                  entp = lists + 2 * CAP_E + (g - c0 - c1);
        w0_edge(entp, n2l, ea_g, W1, b1, W2, b2, Wg, bg, Ww, bw, lane);
    }
}

// Iteration-1 aggregation (the only big edge set, ~4.5k edges): multi-block atomics.
__global__ void agg1_kernel(const int4* __restrict__ list, const int* __restrict__ cnt,
                            const float* __restrict__ Xprev, const float* __restrict__ MVprev,
                            float* __restrict__ agg)
{
    int tid = blockIdx.x * 256 + threadIdx.x;
    int nthr = (int)gridDim.x * 256;
    int c = *cnt; if (c > CAP_E) c = CAP_E;
    int lane = tid & 63;
    for (int i = tid >> 6; i < c; i += (nthr >> 6)) {
        int4 ent = list[i];
        if ((unsigned)ent.x >= MAXLOC || (unsigned)ent.y >= MAXLOC) continue;
        float s = sigm_f(MVprev[ent.x] * __int_as_float(ent.w));
        if (lane < 48) atomicAdd(&agg[ent.y * LF + lane], s * Xprev[ent.x * LF + lane]);
    }
}

// ---- single-block tail: upd1 -> agg2 -> upd2 -> agg3 -> upd3 -> out ----
// Valid because the cone collapses: |S1|~270 nodes, |E2|~270 edges, |S2|~17, |E3|~16.
// Within one block, plain global stores + __syncthreads are workgroup-coherent;
// agg values (written by L2 atomics) are read back with atomicAdd(p, 0.f).

__device__ void upd_block(int nl, const int* __restrict__ l2n, const unsigned* __restrict__ Mt,
                          float* __restrict__ agg, const float* __restrict__ Xp,
                          const float* __restrict__ Vp, const float* __restrict__ Xorig,
                          float* __restrict__ Xc, float* __restrict__ Vc, float* __restrict__ MVc,
                          float wf0, float wf1, float wf2, float bfs, int tid)
{
    for (int loc = tid; loc < nl; loc += 1024) {
        int node = l2n[loc];
        if (!(Mt[node >> 5] & (1u << (node & 31)))) continue;
        float vsum = 0.f;
        #pragma unroll 4
        for (int l = 0; l < LF; ++l) {
            float nh = atomicAdd(&agg[loc * LF + l], 0.f);
            float xo = Xp[loc * LF + l];
            float vp = Vp[loc * LF + l];
            float nv = 1.0f - vp;
            float m = sigm_f(nh * wf0 + xo * wf1 + nv * wf2 + bfs);
            float xn = (1.0f - m) * xo + nv * m * nh;
            float vn = ((Xorig[loc * LF + l] != xn) || (vp > 0.f)) ? 1.0f : 0.0f;
            if (l == 0) vn = 0.0f;
            Xc[loc * LF + l] = xn;
            Vc[loc * LF + l] = vn;
            vsum += vn;
        }
        MVc[loc] = vsum * (1.0f / 48.0f);
    }
}

__device__ void agg_block(const int4* __restrict__ list, int c, const float* __restrict__ Xp,
                          const float* __restrict__ MVp, float* __restrict__ agg, int tid)
{
    int lane = tid & 63;
    for (int i = tid >> 6; i < c; i += 16) {
        int4 ent = list[i];
        if ((unsigned)ent.x >= MAXLOC || (unsigned)ent.y >= MAXLOC) continue;
        float s = sigm_f(MVp[ent.x] * __int_as_float(ent.w));
        if (lane < 48) atomicAdd(&agg[ent.y * LF + lane], s * Xp[ent.x * LF + lane]);
    }
}

__global__ void __launch_bounds__(1024) tail_kernel(
    const int* __restrict__ counters, const int* __restrict__ l2n, const int* __restrict__ n2l,
    const unsigned* __restrict__ M1, const unsigned* __restrict__ M2,
    const int4* __restrict__ lists, const float* __restrict__ X0,
    float* __restrict__ XA, float* __restrict__ XB,
    float* __restrict__ VA, float* __restrict__ VB,
    float* __restrict__ MVA, float* __restrict__ MVB,
    float* __restrict__ agg0, float* __restrict__ agg1b, float* __restrict__ agg2b,
    const float* __restrict__ Wf, const float* __restrict__ bf, float* __restrict__ out)
{
    int tid = threadIdx.x;
    int nl = counters[3]; if (nl > MAXLOC) nl = MAXLOC;
    int c0 = counters[0]; c0 = (c0 > CAP_E) ? CAP_E : c0;
    int c1 = counters[1]; c1 = (c1 > CAP_E) ? CAP_E : c1;
    float wf0 = Wf[0], wf1 = Wf[1], wf2 = Wf[2], bfs = bf[0];

    // iter 1 update: nodes in M1; agg0 from agg1_kernel; X0/VA -> XA/VB/MVB
    upd_block(nl, l2n, M1, agg0, X0, VA, X0, XA, VB, MVB, wf0, wf1, wf2, bfs, tid);
    __syncthreads();
    // iter 2 aggregation: E2 = lists[slot1]
    agg_block(lists + CAP_E, c1, XA, MVB, agg1b, tid);
    __syncthreads();
    // iter 2 update: nodes in M2; XA/VB -> XB/VA/MVA
    upd_block(nl, l2n, M2, agg1b, XA, VB, X0, XB, VA, MVA, wf0, wf1, wf2, bfs, tid);
    __syncthreads();
    // iter 3 aggregation: E3 = lists[slot0] (dst = node 0 only)
    agg_block(lists, c0, XB, MVA, agg2b, tid);
    __syncthreads();
    // iter 3 update for node 0 only -> output row
    if (tid < 48) {
        int loc0 = n2l[0]; if ((unsigned)loc0 >= MAXLOC) loc0 = 0;
        float nh = atomicAdd(&agg2b[loc0 * LF + tid], 0.f);
        float xo = XB[loc0 * LF + tid];
        float vp = VA[loc0 * LF + tid];
        float nv = 1.0f - vp;
        float m = sigm_f(nh * wf0 + xo * wf1 + nv * wf2 + bfs);
        out[tid] = (1.0f - m) * xo + nv * m * nh;
    }
}

extern "C" void kernel_launch(void* const* d_in, const int* in_sizes, int n_in,
                              void* d_out, int out_size, void* d_ws, size_t ws_size,
                              hipStream_t stream)
{
    (void)in_sizes; (void)n_in; (void)out_size;
    const float* nodes = (const float*)d_in[0];
    const int*   eidx  = (const int*)d_in[1];     // (2,E) int32
    const float* eattr = (const float*)d_in[2];
    const float* valid = (const float*)d_in[3];
    // d_in[4]=r, d_in[5]=fx unused by reference
    const float* W1 = (const float*)d_in[6];
    const float* b1 = (const float*)d_in[7];
    const float* W2 = (const float*)d_in[8];
    const float* b2 = (const float*)d_in[9];
    const float* Wg = (const float*)d_in[10];
    const float* bg = (const float*)d_in[11];
    const float* Ww = (const float*)d_in[12];
    const float* bw = (const float*)d_in[13];
    const float* Wf = (const float*)d_in[14];
    const float* bf = (const float*)d_in[15];
    const int* src = eidx;
    const int* dst = eidx + NE;

    char* ws = (char*)d_ws;
    size_t off = 0;
    auto alloc = [&](size_t bytes) -> char* {
        char* p = ws + off;
        off += (bytes + 255) & ~(size_t)255;
        return p;
    };
    // counters + M2 contiguous -> single hipMemsetAsync covers both
    char*     zb = alloc(256 + MASKW * 4);
    int*      counters = (int*)zb;                // [0]=|E3| [1]=|E2| [2]=|E1| [3]=nloc
    unsigned* M2 = (unsigned*)(zb + 256);
    unsigned* M1 = (unsigned*)alloc(MASKW * 4);
    unsigned* M0 = (unsigned*)alloc(MASKW * 4);
    int*      n2l = (int*)alloc((size_t)NN * 4);
    int*      l2n = (int*)alloc((size_t)MAXLOC * 4);
    int4*     lists = (int4*)alloc((size_t)3 * CAP_E * 16); // slot0=E3, slot1=E2, slot2=E1
    float*    X0 = (float*)alloc((size_t)MAXLOC * LF * 4);
    float*    XA = (float*)alloc((size_t)MAXLOC * LF * 4);
    float*    XB = (float*)alloc((size_t)MAXLOC * LF * 4);
    float*    VA = (float*)alloc((size_t)MAXLOC * LF * 4);
    float*    VB = (float*)alloc((size_t)MAXLOC * LF * 4);
    float*    MVA = (float*)alloc((size_t)MAXLOC * 4);
    float*    MVB = (float*)alloc((size_t)MAXLOC * 4);
    float*    agg = (float*)alloc((size_t)3 * MAXLOC * LF * 4); // agg0 | agg1b | agg2b
    if (off > ws_size) return;   // ~23 MB needed; fail loudly rather than corrupt
    float* agg0  = agg;
    float* agg1b = agg + MAXLOC * LF;
    float* agg2b = agg + 2 * MAXLOC * LF;

    hipMemsetAsync(zb, 0, 256 + MASKW * 4, stream);

    // Backward BFS (3 levels), zero-init folded into expand1
    expand1_kernel<<<EB, 256, 0, stream>>>(src, dst, M2, M1, M0, (float4*)agg,
                                           lists + 0 * CAP_E, counters + 0);
    expand_kernel<<<EB, 256, 0, stream>>>(src, dst, M2, M1, lists + 1 * CAP_E, counters + 1);
    expand_kernel<<<EB, 256, 0, stream>>>(src, dst, M1, M0, lists + 2 * CAP_E, counters + 2);
    compact_kernel<<<(MASKW + 255) / 256, 256, 0, stream>>>(M0, n2l, l2n, counters + 3);
    initw0_kernel<<<1024, 256, 0, stream>>>(counters, l2n, n2l, nodes, valid,
                                            X0, VA, MVA, lists, eattr,
                                            W1, b1, W2, b2, Wg, bg, Ww, bw);
    agg1_kernel<<<1024, 256, 0, stream>>>(lists + 2 * CAP_E, counters + 2, X0, MVA, agg0);
    tail_kernel<<<1, 1024, 0, stream>>>(counters, l2n, n2l, M1, M2, lists, X0,
                                        XA, XB, VA, VB, MVA, MVB,
                                        agg0, agg1b, agg2b, Wf, bf, (float*)d_out);
}

// Round 3
// 341.546 us; speedup vs baseline: 2.9606x; 1.1591x over previous
//
#include <hip/hip_runtime.h>
#include <math.h>

// Problem constants (from reference)
#define NN 100000          // nodes
#define LF 48              // features per node
#define NE 1600000         // edges
#define EDIMS 17           // edge_attr dim
#define MASKW 3125         // NN/32 bitmask words
#define CAP_E 16384        // per-level edge-list capacity (expected ~5k max level)
#define MAXLOC 12288       // active-node capacity (expected ~4.9k)
#define EB 1563            // expand grid: ceil(NE/4/256), 4 edges/thread via int4
#define ACT1_CAP 8192      // LDS list of M1-active locs (expected ~280)
#define ACT2_CAP 64        // LDS list of M2-active locs (expected ~17)

static_assert(NN == MASKW * 32, "mask width");
static_assert(NE % 4 == 0, "int4 edge scan");

__device__ __forceinline__ float gelu_f(float x) {
    // jax.nn.gelu(approximate=False) = x * 0.5 * (1 + erf(x/sqrt(2)))
    return 0.5f * x * (1.0f + erff(x * 0.7071067811865475f));
}
__device__ __forceinline__ float sigm_f(float x) {
    return 1.0f / (1.0f + expf(-x));
}
__device__ __forceinline__ float wave_sum(float v) {
    #pragma unroll
    for (int off = 32; off > 0; off >>= 1) v += __shfl_down(v, off, 64);
    return __shfl(v, 0, 64);   // broadcast lane-0 total
}

// Level-3 expand: S3 = {0} implicit (test dst==0). Folds zero-init of M1, M0
// and both agg buffers (all consumed only by later dispatches).
__global__ void expand1_kernel(const int* __restrict__ src, const int* __restrict__ dst,
                               unsigned* __restrict__ M2, unsigned* __restrict__ M1,
                               unsigned* __restrict__ M0, float4* __restrict__ aggz,
                               int4* __restrict__ list0, int* __restrict__ counter)
{
    int tid = blockIdx.x * 256 + threadIdx.x;
    int nthr = (int)gridDim.x * 256;
    for (int i = tid; i < MASKW; i += nthr) { M1[i] = 0u; M0[i] = 0u; }
    for (int i = tid; i < (2 * MAXLOC * LF) / 4; i += nthr)
        aggz[i] = make_float4(0.f, 0.f, 0.f, 0.f);
    if (tid == 0) atomicOr(&M2[0], 1u);   // S2 ⊇ S3 = {0}
    int e0 = tid * 4;
    if (e0 + 3 < NE) {
        int4 d4 = *(const int4*)(dst + e0);
        int dv[4] = { d4.x, d4.y, d4.z, d4.w };
        #pragma unroll
        for (int k = 0; k < 4; ++k) {
            if (dv[k] == 0) {
                int e = e0 + k;
                int s = src[e];
                int idx = atomicAdd(counter, 1);
                if (idx < CAP_E) list0[idx] = make_int4(s, 0, e, 0);
                atomicOr(&M2[s >> 5], 1u << (s & 31));
            }
        }
    }
}

// Level-2 expand: M1 (pre-zeroed) := M2 | src-bits of edges with dst in M2; append edges.
__global__ void expand2_kernel(const int* __restrict__ src, const int* __restrict__ dst,
                               const unsigned* __restrict__ Min, unsigned* __restrict__ Mout,
                               int4* __restrict__ list, int* __restrict__ counter)
{
    int tid = blockIdx.x * 256 + threadIdx.x;
    int nthr = (int)gridDim.x * 256;
    for (int i = tid; i < MASKW; i += nthr) {
        unsigned m = Min[i];
        if (m) atomicOr(&Mout[i], m);
    }
    int e0 = tid * 4;
    if (e0 + 3 < NE) {
        int4 d4 = *(const int4*)(dst + e0);
        int dv[4] = { d4.x, d4.y, d4.z, d4.w };
        #pragma unroll
        for (int k = 0; k < 4; ++k) {
            int d = dv[k];
            if (Min[d >> 5] & (1u << (d & 31))) {
                int e = e0 + k;
                int s = src[e];
                int idx = atomicAdd(counter, 1);
                if (idx < CAP_E) list[idx] = make_int4(s, d, e, 0);
                atomicOr(&Mout[s >> 5], 1u << (s & 31));
            }
        }
    }
}

// Level-1 expand WITH inline loc assignment (replaces compact_kernel).
// S0 = S1 ∪ src(E1). M1-bit nodes are assigned by the word-owner thread (unique);
// new src nodes assign exactly once via the atomicOr 0->1 transition on scratch M0,
// guarded by "not in M1" so they don't double with the word-owner path.
__global__ void expand3_kernel(const int* __restrict__ src, const int* __restrict__ dst,
                               const unsigned* __restrict__ M1, unsigned* __restrict__ M0,
                               int4* __restrict__ list, int* __restrict__ counter,
                               int* __restrict__ n2l, int* __restrict__ l2n,
                               int* __restrict__ nloc)
{
    int tid = blockIdx.x * 256 + threadIdx.x;
    int nthr = (int)gridDim.x * 256;
    for (int w = tid; w < MASKW; w += nthr) {
        unsigned bits = M1[w];
        while (bits) {
            int b = __ffs(bits) - 1;
            bits &= bits - 1;
            int node = w * 32 + b;
            int loc = atomicAdd(nloc, 1);
            if (loc < MAXLOC) { n2l[node] = loc; l2n[loc] = node; }
        }
    }
    int e0 = tid * 4;
    if (e0 + 3 < NE) {
        int4 d4 = *(const int4*)(dst + e0);
        int dv[4] = { d4.x, d4.y, d4.z, d4.w };
        #pragma unroll
        for (int k = 0; k < 4; ++k) {
            int d = dv[k];
            if (M1[d >> 5] & (1u << (d & 31))) {
                int e = e0 + k;
                int s = src[e];
                int idx = atomicAdd(counter, 1);
                if (idx < CAP_E) list[idx] = make_int4(s, d, e, 0);
                unsigned sb = 1u << (s & 31);
                unsigned old = atomicOr(&M0[s >> 5], sb);
                if (!(old & sb) && !(M1[s >> 5] & sb)) {
                    int loc = atomicAdd(nloc, 1);
                    if (loc < MAXLOC) { n2l[s] = loc; l2n[loc] = s; }
                }
            }
        }
    }
}

// Per-edge loop-invariant MLP scalar, wave-cooperative (64 lanes, no LDS/syncthreads):
//   w0 = gelu(relu(gelu(ea@W1+b1)@W2+b2)@Wg+bg)@Ww + bw    (broadcast to all lanes)
__device__ float w0_compute(long e, const float* __restrict__ ea_g,
                            const float* __restrict__ W1, const float* __restrict__ b1,
                            const float* __restrict__ W2, const float* __restrict__ b2,
                            const float* __restrict__ Wg, const float* __restrict__ bg,
                            const float* __restrict__ Ww, const float* __restrict__ bw,
                            int lane)
{
    float ea = 0.f;
    if (lane < EDIMS) ea = ea_g[e * EDIMS + lane];
    float h1 = 0.f;
    if (lane < 48) {
        float acc = b1[lane];
        #pragma unroll
        for (int k = 0; k < EDIMS; ++k) acc += __shfl(ea, k, 64) * W1[k * 48 + lane];
        h1 = gelu_f(acc);
    }
    float h2 = 0.f;
    if (lane < 48) {
        float acc = b2[lane];
        #pragma unroll 8
        for (int k = 0; k < 48; ++k) acc += __shfl(h1, k, 64) * W2[k * 48 + lane];
        h2 = fmaxf(acc, 0.f);
    }
    float part = 0.f;
    if (lane < 48) {
        float acc = bg[lane];
        #pragma unroll 8
        for (int k = 0; k < 48; ++k) acc += __shfl(h2, k, 64) * Wg[k * 48 + lane];
        part = gelu_f(acc) * Ww[lane];
    }
    return wave_sum(part) + bw[0];
}

// Fused: (a) init X0/VA for M1-active locs only (~280 nodes; all later reads are M1-local);
// (b) per-edge w0 for all 3 lists; E1 edges additionally do the iter-1 aggregation
// directly from RAW inputs (x0[src]=nodes*valid, mv0[src]=mean(valid)) -> no dependency
// on part (a), so the former agg1 dispatch disappears.
__global__ void fused_kernel(const int* __restrict__ counters, const int* __restrict__ l2n,
                             const int* __restrict__ n2l, const unsigned* __restrict__ M1,
                             const float* __restrict__ nodes, const float* __restrict__ valid,
                             float* __restrict__ X0, float* __restrict__ VA,
                             int4* __restrict__ lists, const float* __restrict__ ea_g,
                             const float* __restrict__ W1, const float* __restrict__ b1,
                             const float* __restrict__ W2, const float* __restrict__ b2,
                             const float* __restrict__ Wg, const float* __restrict__ bg,
                             const float* __restrict__ Ww, const float* __restrict__ bw,
                             float* __restrict__ agg0)
{
    int tid = blockIdx.x * 256 + threadIdx.x;
    int nthr = (int)gridDim.x * 256;
    int nl = counters[3]; if (nl > MAXLOC) nl = MAXLOC;
    for (int loc = tid; loc < nl; loc += nthr) {
        int node = l2n[loc];
        if (!(M1[node >> 5] & (1u << (node & 31)))) continue;
        const float4* nv = (const float4*)(valid + (size_t)node * LF);
        const float4* nx = (const float4*)(nodes + (size_t)node * LF);
        float4* X0v = (float4*)(X0 + (size_t)loc * LF);
        float4* V0v = (float4*)(VA + (size_t)loc * LF);
        #pragma unroll
        for (int k = 0; k < 12; ++k) {
            float4 v = nv[k], x = nx[k];
            x.x *= v.x; x.y *= v.y; x.z *= v.z; x.w *= v.w;
            X0v[k] = x; V0v[k] = v;
        }
    }
    int c0 = counters[0]; c0 = (c0 > CAP_E) ? CAP_E : c0;
    int c1 = counters[1]; c1 = (c1 > CAP_E) ? CAP_E : c1;
    int c2 = counters[2]; c2 = (c2 > CAP_E) ? CAP_E : c2;
    int total = c0 + c1 + c2;
    int lane = tid & 63;
    for (int g = tid >> 6; g < total; g += (nthr >> 6)) {
        int4* entp;
        bool isE1 = false;
        if (g < c0)           entp = lists + g;
        else if (g < c0 + c1) entp = lists + CAP_E + (g - c0);
        else                { entp = lists + 2 * CAP_E + (g - c0 - c1); isE1 = true; }
        int4 ent = *entp;
        float w0 = w0_compute((long)ent.z, ea_g, W1, b1, W2, b2, Wg, bg, Ww, bw, lane);
        if (isE1) {
            int s = ent.x;                          // global node id
            int dl = n2l[ent.y]; if ((unsigned)dl >= MAXLOC) dl = 0;
            float v = 0.f, x = 0.f;
            if (lane < 48) {
                v = valid[(size_t)s * LF + lane];
                x = nodes[(size_t)s * LF + lane] * v;
            }
            float mv = wave_sum(v) * (1.0f / 48.0f);
            float sg = sigm_f(mv * w0);
            if (lane < 48) atomicAdd(&agg0[dl * LF + lane], sg * x);
        } else if (lane == 0) {
            int sl = n2l[ent.x]; if ((unsigned)sl >= MAXLOC) sl = 0;
            int dl = n2l[ent.y]; if ((unsigned)dl >= MAXLOC) dl = 0;
            *entp = make_int4(sl, dl, ent.z, __float_as_int(w0));
        }
    }
}

// ---- single-block tail: upd1 -> agg2 -> upd2 -> agg3 -> upd3 -> out ----
// Wave-per-node (lane = feature) for coalesced 192B rows; active lists compacted to
// LDS up-front; agg3 (dst = node 0 only) accumulated in LDS.
__global__ void __launch_bounds__(1024) tail_kernel(
    const int* __restrict__ counters, const int* __restrict__ l2n, const int* __restrict__ n2l,
    const unsigned* __restrict__ M1, const unsigned* __restrict__ M2,
    const int4* __restrict__ lists, const float* __restrict__ X0,
    float* __restrict__ XA, float* __restrict__ XB,
    float* __restrict__ VA, float* __restrict__ VB,
    float* __restrict__ MVA, float* __restrict__ MVB,
    const float* __restrict__ agg0, float* __restrict__ agg1b,
    const float* __restrict__ Wf, const float* __restrict__ bf, float* __restrict__ out)
{
    __shared__ int act1[ACT1_CAP];
    __shared__ int act2[ACT2_CAP];
    __shared__ int cnts[2];
    __shared__ float agg3s[LF];
    int tid = threadIdx.x;
    if (tid < 2) cnts[tid] = 0;
    if (tid < LF) agg3s[tid] = 0.f;
    __syncthreads();

    int nl = counters[3]; if (nl > MAXLOC) nl = MAXLOC;
    for (int loc = tid; loc < nl; loc += 1024) {
        int node = l2n[loc];
        unsigned bit = 1u << (node & 31);
        unsigned w1 = M1[node >> 5], w2 = M2[node >> 5];
        if (w1 & bit) { int i = atomicAdd(&cnts[0], 1); if (i < ACT1_CAP) act1[i] = loc; }
        if (w2 & bit) { int i = atomicAdd(&cnts[1], 1); if (i < ACT2_CAP) act2[i] = loc; }
    }
    __syncthreads();
    int c1n = cnts[0]; if (c1n > ACT1_CAP) c1n = ACT1_CAP;
    int c2n = cnts[1]; if (c2n > ACT2_CAP) c2n = ACT2_CAP;
    int wave = tid >> 6, lane = tid & 63;
    float wf0 = Wf[0], wf1 = Wf[1], wf2 = Wf[2], bfs = bf[0];

    // iter-1 update: nodes in M1; X0/VA -> XA/VB/MVB  (Xp == Xorig == X0 here)
    for (int i = wave; i < c1n; i += 16) {
        int loc = act1[i];
        float nh = 0.f, xo = 0.f, vp = 0.f;
        if (lane < 48) {
            nh = agg0[loc * LF + lane];
            xo = X0[loc * LF + lane];
            vp = VA[loc * LF + lane];
        }
        float nv = 1.0f - vp;
        float m = sigm_f(nh * wf0 + xo * wf1 + nv * wf2 + bfs);
        float xn = (1.0f - m) * xo + nv * m * nh;
        float vn = ((xo != xn) || (vp > 0.f)) ? 1.0f : 0.0f;
        if (lane == 0) vn = 0.0f;
        if (lane < 48) { XA[loc * LF + lane] = xn; VB[loc * LF + lane] = vn; }
        float s = (lane < 48) ? vn : 0.f;
        #pragma unroll
        for (int off = 32; off > 0; off >>= 1) s += __shfl_down(s, off, 64);
        if (lane == 0) MVB[loc] = s * (1.0f / 48.0f);
    }
    __syncthreads();

    // iter-2 aggregation: E2 (slot1), wave-per-edge -> agg1b (global atomics, ~270 edges)
    int cE2 = counters[1]; if (cE2 > CAP_E) cE2 = CAP_E;
    for (int i = wave; i < cE2; i += 16) {
        int4 ent = lists[CAP_E + i];
        if ((unsigned)ent.x >= MAXLOC || (unsigned)ent.y >= MAXLOC) continue;
        float sg = sigm_f(MVB[ent.x] * __int_as_float(ent.w));
        if (lane < 48) atomicAdd(&agg1b[ent.y * LF + lane], sg * XA[ent.x * LF + lane]);
    }
    __syncthreads();

    // iter-2 update: nodes in M2; XA/VB -> XB/VA/MVA  (Xorig = X0)
    for (int i = wave; i < c2n; i += 16) {
        int loc = act2[i];
        float nh = 0.f, xo = 0.f, vp = 0.f, xorig = 0.f;
        if (lane < 48) {
            nh = agg1b[loc * LF + lane];
            xo = XA[loc * LF + lane];
            vp = VB[loc * LF + lane];
            xorig = X0[loc * LF + lane];
        }
        float nv = 1.0f - vp;
        float m = sigm_f(nh * wf0 + xo * wf1 + nv * wf2 + bfs);
        float xn = (1.0f - m) * xo + nv * m * nh;
        float vn = ((xorig != xn) || (vp > 0.f)) ? 1.0f : 0.0f;
        if (lane == 0) vn = 0.0f;
        if (lane < 48) { XB[loc * LF + lane] = xn; VA[loc * LF + lane] = vn; }
        float s = (lane < 48) ? vn : 0.f;
        #pragma unroll
        for (int off = 32; off > 0; off >>= 1) s += __shfl_down(s, off, 64);
        if (lane == 0) MVA[loc] = s * (1.0f / 48.0f);
    }
    __syncthreads();

    // iter-3 aggregation: E3 (slot0), dst = node 0 only -> LDS accumulator
    int cE3 = counters[0]; if (cE3 > CAP_E) cE3 = CAP_E;
    for (int i = wave; i < cE3; i += 16) {
        int4 ent = lists[i];
        if ((unsigned)ent.x >= MAXLOC) continue;
        float sg = sigm_f(MVA[ent.x] * __int_as_float(ent.w));
        if (lane < 48) atomicAdd(&agg3s[lane], sg * XB[ent.x * LF + lane]);
    }
    __syncthreads();

    // iter-3 update for node 0 -> output row
    if (tid < 48) {
        int loc0 = n2l[0]; if ((unsigned)loc0 >= MAXLOC) loc0 = 0;
        float nh = agg3s[tid];
        float xo = XB[loc0 * LF + tid];
        float vp = VA[loc0 * LF + tid];
        float nv = 1.0f - vp;
        float m = sigm_f(nh * wf0 + xo * wf1 + nv * wf2 + bfs);
        out[tid] = (1.0f - m) * xo + nv * m * nh;
    }
}

extern "C" void kernel_launch(void* const* d_in, const int* in_sizes, int n_in,
                              void* d_out, int out_size, void* d_ws, size_t ws_size,
                              hipStream_t stream)
{
    (void)in_sizes; (void)n_in; (void)out_size;
    const float* nodes = (const float*)d_in[0];
    const int*   eidx  = (const int*)d_in[1];     // (2,E) int32
    const float* eattr = (const float*)d_in[2];
    const float* valid = (const float*)d_in[3];
    // d_in[4]=r, d_in[5]=fx unused by reference
    const float* W1 = (const float*)d_in[6];
    const float* b1 = (const float*)d_in[7];
    const float* W2 = (const float*)d_in[8];
    const float* b2 = (const float*)d_in[9];
    const float* Wg = (const float*)d_in[10];
    const float* bg = (const float*)d_in[11];
    const float* Ww = (const float*)d_in[12];
    const float* bw = (const float*)d_in[13];
    const float* Wf = (const float*)d_in[14];
    const float* bf = (const float*)d_in[15];
    const int* src = eidx;
    const int* dst = eidx + NE;

    char* ws = (char*)d_ws;
    size_t off = 0;
    auto alloc = [&](size_t bytes) -> char* {
        char* p = ws + off;
        off += (bytes + 255) & ~(size_t)255;
        return p;
    };
    // counters + M2 contiguous -> single hipMemsetAsync covers both
    char*     zb = alloc(256 + MASKW * 4);
    int*      counters = (int*)zb;                // [0]=|E3| [1]=|E2| [2]=|E1| [3]=nloc
    unsigned* M2 = (unsigned*)(zb + 256);
    unsigned* M1 = (unsigned*)alloc(MASKW * 4);
    unsigned* M0 = (unsigned*)alloc(MASKW * 4);   // scratch dedup mask for expand3
    int*      n2l = (int*)alloc((size_t)NN * 4);
    int*      l2n = (int*)alloc((size_t)MAXLOC * 4);
    int4*     lists = (int4*)alloc((size_t)3 * CAP_E * 16); // slot0=E3, slot1=E2, slot2=E1
    float*    X0 = (float*)alloc((size_t)MAXLOC * LF * 4);
    float*    XA = (float*)alloc((size_t)MAXLOC * LF * 4);
    float*    XB = (float*)alloc((size_t)MAXLOC * LF * 4);
    float*    VA = (float*)alloc((size_t)MAXLOC * LF * 4);
    float*    VB = (float*)alloc((size_t)MAXLOC * LF * 4);
    float*    MVA = (float*)alloc((size_t)MAXLOC * 4);
    float*    MVB = (float*)alloc((size_t)MAXLOC * 4);
    float*    agg = (float*)alloc((size_t)2 * MAXLOC * LF * 4); // agg0 | agg1b
    if (off > ws_size) return;   // ~18 MB needed; fail loudly rather than corrupt
    float* agg0  = agg;
    float* agg1b = agg + MAXLOC * LF;

    hipMemsetAsync(zb, 0, 256 + MASKW * 4, stream);

    // Backward BFS (3 levels); zero-init folded into expand1; loc-assign folded into expand3
    expand1_kernel<<<EB, 256, 0, stream>>>(src, dst, M2, M1, M0, (float4*)agg,
                                           lists + 0 * CAP_E, counters + 0);
    expand2_kernel<<<EB, 256, 0, stream>>>(src, dst, M2, M1, lists + 1 * CAP_E, counters + 1);
    expand3_kernel<<<EB, 256, 0, stream>>>(src, dst, M1, M0, lists + 2 * CAP_E, counters + 2,
                                           n2l, l2n, counters + 3);
    fused_kernel<<<1024, 256, 0, stream>>>(counters, l2n, n2l, M1, nodes, valid,
                                           X0, VA, lists, eattr,
                                           W1, b1, W2, b2, Wg, bg, Ww, bw, agg0);
    tail_kernel<<<1, 1024, 0, stream>>>(counters, l2n, n2l, M1, M2, lists, X0,
                                        XA, XB, VA, VB, MVA, MVB,
                                        agg0, agg1b, Wf, bf, (float*)d_out);
}